// Round 2
// baseline (342.142 us; speedup 1.0000x reference)
//
#include <hip/hip_runtime.h>

#define DEVINL __device__ __forceinline__

// lower-tri packed index, requires i >= j
#define TIX(i, j) ((i) * ((i) + 1) / 2 + (j))
// symmetric access (compile-time resolved under full unroll)
#define SYM(arr, i, j) ((i) >= (j) ? arr[TIX(i, j)] : arr[TIX(j, i)])

DEVINL void inv4(const float* m, float* inv) {
    float s0 = m[0] * m[5] - m[1] * m[4];
    float s1 = m[0] * m[6] - m[2] * m[4];
    float s2 = m[0] * m[7] - m[3] * m[4];
    float s3 = m[1] * m[6] - m[2] * m[5];
    float s4 = m[1] * m[7] - m[3] * m[5];
    float s5 = m[2] * m[7] - m[3] * m[6];
    float c5 = m[10] * m[15] - m[11] * m[14];
    float c4 = m[9] * m[15] - m[11] * m[13];
    float c3 = m[9] * m[14] - m[10] * m[13];
    float c2 = m[8] * m[15] - m[11] * m[12];
    float c1 = m[8] * m[14] - m[10] * m[12];
    float c0 = m[8] * m[13] - m[9] * m[12];
    float det = s0 * c5 - s1 * c4 + s2 * c3 + s3 * c2 - s4 * c1 + s5 * c0;
    float id = 1.0f / det;
    inv[0]  = ( m[5] * c5 - m[6] * c4 + m[7] * c3) * id;
    inv[1]  = (-m[1] * c5 + m[2] * c4 - m[3] * c3) * id;
    inv[2]  = ( m[13] * s5 - m[14] * s4 + m[15] * s3) * id;
    inv[3]  = (-m[9] * s5 + m[10] * s4 - m[11] * s3) * id;
    inv[4]  = (-m[4] * c5 + m[6] * c2 - m[7] * c1) * id;
    inv[5]  = ( m[0] * c5 - m[2] * c2 + m[3] * c1) * id;
    inv[6]  = (-m[12] * s5 + m[14] * s2 - m[15] * s1) * id;
    inv[7]  = ( m[8] * s5 - m[10] * s2 + m[11] * s1) * id;
    inv[8]  = ( m[4] * c4 - m[5] * c2 + m[7] * c0) * id;
    inv[9]  = (-m[0] * c4 + m[1] * c2 - m[3] * c0) * id;
    inv[10] = ( m[12] * s4 - m[13] * s2 + m[15] * s0) * id;
    inv[11] = (-m[8] * s4 + m[9] * s2 - m[11] * s0) * id;
    inv[12] = (-m[4] * c3 + m[5] * c1 - m[6] * c0) * id;
    inv[13] = ( m[0] * c3 - m[1] * c1 + m[2] * c0) * id;
    inv[14] = (-m[12] * s3 + m[13] * s1 - m[14] * s0) * id;
    inv[15] = ( m[8] * s3 - m[9] * s1 + m[10] * s0) * id;
}

// One thread per batch; 256 batches per 256-thread block.
// All large global traffic goes through one reused LDS buffer with
// coalesced global access; LDS rows padded to 9 float4s (bank spread).
__global__ __launch_bounds__(256, 3) void ekf_kernel(
    const float* __restrict__ meas,   // (B,4)
    const float* __restrict__ state,  // (B,8)
    const float* __restrict__ Pin,    // (B,8,8) symmetric
    const float* __restrict__ Fin,    // (B,8,8)
    const float* __restrict__ Hin,    // (B,4,8)
    const float* __restrict__ pnin,   // (B,36)
    const float* __restrict__ mnin,   // (B,10)
    float* __restrict__ out_pred,     // (B,4)
    float* __restrict__ out_state,    // (B,8)
    float* __restrict__ out_cov,      // (B,8,8)
    int B)
{
    const int t  = threadIdx.x;
    const int bb = blockIdx.x * 256;          // batch base of this block
    const int nb = min(256, B - bb);          // valid batches in this block
    const int b  = bb + t;
    const bool act = (t < nb);

    __shared__ float4 buf[2304];              // 256 * 9 float4 = 36,864 B

    // ============ stage pn (9 f4/batch, straight copy) -> Q into Pn ============
    {
        const float4* g = reinterpret_cast<const float4*>(pnin) + (size_t)bb * 9;
        const int lim = nb * 9;
        #pragma unroll
        for (int i = 0; i < 9; ++i) { int f = i * 256 + t; if (f < lim) buf[f] = g[f]; }
    }
    __syncthreads();
    float Pn[36];  // becomes new_state_cov; init with Q
    if (act) {
        float Lq[36];
        #pragma unroll
        for (int q = 0; q < 9; ++q) {
            float4 v = buf[t * 9 + q];
            Lq[4 * q] = v.x; Lq[4 * q + 1] = v.y; Lq[4 * q + 2] = v.z; Lq[4 * q + 3] = v.w;
        }
        #pragma unroll
        for (int i = 0; i < 8; ++i)
            #pragma unroll
            for (int j = 0; j <= i; ++j) {
                float acc = 0.f;
                #pragma unroll
                for (int k = 0; k <= j; ++k)
                    acc += Lq[TIX(i, k)] * Lq[TIX(j, k)];
                Pn[TIX(i, j)] = acc;
            }
    }
    __syncthreads();

    // ============ stage state (2 f4/batch, pad-3 layout) ============
    {
        const float4* g = reinterpret_cast<const float4*>(state) + (size_t)bb * 2;
        const int lim = nb * 2;
        #pragma unroll
        for (int i = 0; i < 2; ++i) {
            int f = i * 256 + t;
            if (f < lim) buf[(f >> 1) * 3 + (f & 1)] = g[f];
        }
    }
    __syncthreads();
    float s[8];
    if (act) {
        float4 a = buf[t * 3 + 0], c = buf[t * 3 + 1];
        s[0] = a.x; s[1] = a.y; s[2] = a.z; s[3] = a.w;
        s[4] = c.x; s[5] = c.y; s[6] = c.z; s[7] = c.w;
    }
    __syncthreads();

    // ============ stage P in two halves (8 f4/batch each, pad-9) -> Ps packed ============
    float Ps[36];
    #pragma unroll
    for (int h = 0; h < 2; ++h) {
        {
            const float4* g = reinterpret_cast<const float4*>(Pin) + (size_t)bb * 16;
            #pragma unroll
            for (int i = 0; i < 8; ++i) {
                int fl = i * 256 + t;
                int bq = fl >> 3, q = fl & 7;
                if (bq < nb) buf[bq * 9 + q] = g[bq * 16 + 8 * h + q];
            }
        }
        __syncthreads();
        if (act) {
            #pragma unroll
            for (int q = 0; q < 8; ++q) {
                float4 v = buf[t * 9 + q];
                const int row = 4 * h + (q >> 1), c0 = 4 * (q & 1);
                if (c0 + 0 <= row) Ps[TIX(row, c0 + 0)] = v.x;
                if (c0 + 1 <= row) Ps[TIX(row, c0 + 1)] = v.y;
                if (c0 + 2 <= row) Ps[TIX(row, c0 + 2)] = v.z;
                if (c0 + 3 <= row) Ps[TIX(row, c0 + 3)] = v.w;
            }
        }
        __syncthreads();
    }

    // ============ stage F in two halves -> Fm[64] ============
    float Fm[64];
    #pragma unroll
    for (int h = 0; h < 2; ++h) {
        {
            const float4* g = reinterpret_cast<const float4*>(Fin) + (size_t)bb * 16;
            #pragma unroll
            for (int i = 0; i < 8; ++i) {
                int fl = i * 256 + t;
                int bq = fl >> 3, q = fl & 7;
                if (bq < nb) buf[bq * 9 + q] = g[bq * 16 + 8 * h + q];
            }
        }
        __syncthreads();
        if (act) {
            #pragma unroll
            for (int q = 0; q < 8; ++q) {
                float4 v = buf[t * 9 + q];
                Fm[32 * h + 4 * q + 0] = v.x;
                Fm[32 * h + 4 * q + 1] = v.y;
                Fm[32 * h + 4 * q + 2] = v.z;
                Fm[32 * h + 4 * q + 3] = v.w;
            }
        }
        __syncthreads();
    }

    // ============ predict ============
    float ns[8];
    if (act) {
        #pragma unroll
        for (int i = 0; i < 8; ++i) {
            float acc = 0.f;
            #pragma unroll
            for (int j = 0; j < 8; ++j) acc += Fm[i * 8 + j] * s[j];
            ns[i] = acc;
        }
        // newP = F P F^T + Q, column block at a time (no T[64])
        #pragma unroll
        for (int l = 0; l < 8; ++l) {
            float gcol[8];  // gcol[j] = (P F^T)[j][l] = sum_k P[j,k] F[l,k]
            #pragma unroll
            for (int j = 0; j < 8; ++j) {
                float acc = 0.f;
                #pragma unroll
                for (int k = 0; k < 8; ++k) acc += SYM(Ps, j, k) * Fm[l * 8 + k];
                gcol[j] = acc;
            }
            #pragma unroll
            for (int i = l; i < 8; ++i) {
                float acc = Pn[TIX(i, l)];
                #pragma unroll
                for (int j = 0; j < 8; ++j) acc += Fm[i * 8 + j] * gcol[j];
                Pn[TIX(i, l)] = acc;
            }
        }
    }

    // ============ stage H (8 f4/batch straight global, pad-9 dest) -> Hm ============
    float Hm[32];
    {
        const float4* g = reinterpret_cast<const float4*>(Hin) + (size_t)bb * 8;
        const int lim = nb * 8;
        #pragma unroll
        for (int i = 0; i < 8; ++i) {
            int fl = i * 256 + t;
            if (fl < lim) buf[(fl >> 3) * 9 + (fl & 7)] = g[fl];
        }
    }
    __syncthreads();
    if (act) {
        #pragma unroll
        for (int q = 0; q < 8; ++q) {
            float4 v = buf[t * 9 + q];
            Hm[4 * q + 0] = v.x; Hm[4 * q + 1] = v.y;
            Hm[4 * q + 2] = v.z; Hm[4 * q + 3] = v.w;
        }
    }
    __syncthreads();

    // ============ stage mn (5 f2/batch straight copy) -> Rs ============
    float Rs[10];
    {
        const float2* g = reinterpret_cast<const float2*>(mnin) + (size_t)bb * 5;
        float2* buf2 = reinterpret_cast<float2*>(buf);
        const int lim = nb * 5;
        #pragma unroll
        for (int i = 0; i < 5; ++i) { int f = i * 256 + t; if (f < lim) buf2[f] = g[f]; }
    }
    __syncthreads();
    if (act) {
        const float2* buf2 = reinterpret_cast<const float2*>(buf);
        float Lr[10];
        #pragma unroll
        for (int p = 0; p < 5; ++p) {
            float2 v = buf2[t * 5 + p];
            Lr[2 * p] = v.x; Lr[2 * p + 1] = v.y;
        }
        #pragma unroll
        for (int i = 0; i < 4; ++i)
            #pragma unroll
            for (int j = 0; j <= i; ++j) {
                float acc = 0.f;
                #pragma unroll
                for (int k = 0; k <= j; ++k)
                    acc += Lr[TIX(i, k)] * Lr[TIX(j, k)];
                Rs[TIX(i, j)] = acc;
            }
    }
    __syncthreads();

    // ============ update (all in registers) ============
    float pred[4], res[4], HP[32], Si[16], K[32], us[8];
    if (act) {
        float4 z = *(reinterpret_cast<const float4*>(meas) + b);
        const float zz[4] = {z.x, z.y, z.z, z.w};
        #pragma unroll
        for (int i = 0; i < 4; ++i) {
            float acc = 0.f;
            #pragma unroll
            for (int j = 0; j < 8; ++j) acc += Hm[i * 8 + j] * ns[j];
            pred[i] = acc;
            res[i] = zz[i] - acc;
        }

        // HP = H * newP (4x8); PHt = HP^T by symmetry of newP
        #pragma unroll
        for (int i = 0; i < 4; ++i)
            #pragma unroll
            for (int k = 0; k < 8; ++k) {
                float acc = 0.f;
                #pragma unroll
                for (int j = 0; j < 8; ++j) acc += Hm[i * 8 + j] * SYM(Pn, j, k);
                HP[i * 8 + k] = acc;
            }

        // S = HP H^T + R -> inverse
        float Sf[16];
        #pragma unroll
        for (int i = 0; i < 4; ++i)
            #pragma unroll
            for (int l = 0; l < 4; ++l) {
                float acc = SYM(Rs, i, l);
                #pragma unroll
                for (int k = 0; k < 8; ++k) acc += HP[i * 8 + k] * Hm[l * 8 + k];
                Sf[i * 4 + l] = acc;
            }
        inv4(Sf, Si);

        // K = PHt * Si (8x4)
        #pragma unroll
        for (int i = 0; i < 8; ++i)
            #pragma unroll
            for (int j = 0; j < 4; ++j) {
                float acc = 0.f;
                #pragma unroll
                for (int k = 0; k < 4; ++k) acc += HP[k * 8 + i] * Si[k * 4 + j];
                K[i * 4 + j] = acc;
            }

        // pred out (direct, fully coalesced: 16B/lane contiguous)
        *(reinterpret_cast<float4*>(out_pred) + b) =
            make_float4(pred[0], pred[1], pred[2], pred[3]);

        #pragma unroll
        for (int i = 0; i < 8; ++i) {
            float acc = ns[i];
            #pragma unroll
            for (int j = 0; j < 4; ++j) acc += K[i * 4 + j] * res[j];
            us[i] = acc;
        }
    }

    // ============ stage upd_state out (pad-3 layout) ============
    __syncthreads();
    if (act) {
        buf[t * 3 + 0] = make_float4(us[0], us[1], us[2], us[3]);
        buf[t * 3 + 1] = make_float4(us[4], us[5], us[6], us[7]);
    }
    __syncthreads();
    {
        float4* g = reinterpret_cast<float4*>(out_state) + (size_t)bb * 2;
        const int lim = nb * 2;
        #pragma unroll
        for (int i = 0; i < 2; ++i) {
            int f = i * 256 + t;
            if (f < lim) g[f] = buf[(f >> 1) * 3 + (f & 1)];
        }
    }
    __syncthreads();

    // ============ upd_cov = (I - K H) newP, two row-halves through LDS ============
    #pragma unroll
    for (int h = 0; h < 2; ++h) {
        if (act) {
            #pragma unroll
            for (int r = 0; r < 4; ++r) {
                const int i = 4 * h + r;
                float Arow[8];
                #pragma unroll
                for (int j = 0; j < 8; ++j) {
                    float acc = (i == j) ? 1.f : 0.f;
                    #pragma unroll
                    for (int k = 0; k < 4; ++k) acc -= K[i * 4 + k] * Hm[k * 8 + j];
                    Arow[j] = acc;
                }
                float orow[8];
                #pragma unroll
                for (int j = 0; j < 8; ++j) {
                    float acc = 0.f;
                    #pragma unroll
                    for (int k = 0; k < 8; ++k) acc += Arow[k] * SYM(Pn, k, j);
                    orow[j] = acc;
                }
                buf[t * 9 + 2 * r + 0] = make_float4(orow[0], orow[1], orow[2], orow[3]);
                buf[t * 9 + 2 * r + 1] = make_float4(orow[4], orow[5], orow[6], orow[7]);
            }
        }
        __syncthreads();
        {
            float4* g = reinterpret_cast<float4*>(out_cov) + (size_t)bb * 16;
            #pragma unroll
            for (int i = 0; i < 8; ++i) {
                int fl = i * 256 + t;
                int bq = fl >> 3, q = fl & 7;
                if (bq < nb) g[bq * 16 + 8 * h + q] = buf[bq * 9 + q];
            }
        }
        __syncthreads();
    }
}

extern "C" void kernel_launch(void* const* d_in, const int* in_sizes, int n_in,
                              void* d_out, int out_size, void* d_ws, size_t ws_size,
                              hipStream_t stream) {
    const float* meas  = (const float*)d_in[0];
    const float* state = (const float*)d_in[1];
    const float* Pin   = (const float*)d_in[2];
    const float* Fin   = (const float*)d_in[3];
    const float* Hin   = (const float*)d_in[4];
    const float* pn    = (const float*)d_in[5];
    const float* mn    = (const float*)d_in[6];

    const int B = in_sizes[1] / 8;  // state is (B, 8)

    float* out = (float*)d_out;
    float* out_pred  = out;                       // B*4
    float* out_state = out + (size_t)B * 4;       // B*8
    float* out_cov   = out + (size_t)B * 12;      // B*64

    dim3 block(256);
    dim3 grid((B + 255) / 256);
    ekf_kernel<<<grid, block, 0, stream>>>(meas, state, Pin, Fin, Hin, pn, mn,
                                           out_pred, out_state, out_cov, B);
}

// Round 3
// 261.729 us; speedup vs baseline: 1.3072x; 1.3072x over previous
//
#include <hip/hip_runtime.h>

#define DEVINL __device__ __forceinline__

// lower-tri packed index, requires i >= j
#define TIX(i, j) ((i) * ((i) + 1) / 2 + (j))
// symmetric access (compile-time resolved under full unroll)
#define SYM(arr, i, j) ((i) >= (j) ? arr[TIX(i, j)] : arr[TIX(j, i)])

DEVINL void inv4(const float* m, float* inv) {
    float s0 = m[0] * m[5] - m[1] * m[4];
    float s1 = m[0] * m[6] - m[2] * m[4];
    float s2 = m[0] * m[7] - m[3] * m[4];
    float s3 = m[1] * m[6] - m[2] * m[5];
    float s4 = m[1] * m[7] - m[3] * m[5];
    float s5 = m[2] * m[7] - m[3] * m[6];
    float c5 = m[10] * m[15] - m[11] * m[14];
    float c4 = m[9] * m[15] - m[11] * m[13];
    float c3 = m[9] * m[14] - m[10] * m[13];
    float c2 = m[8] * m[15] - m[11] * m[12];
    float c1 = m[8] * m[14] - m[10] * m[12];
    float c0 = m[8] * m[13] - m[9] * m[12];
    float det = s0 * c5 - s1 * c4 + s2 * c3 + s3 * c2 - s4 * c1 + s5 * c0;
    float id = 1.0f / det;
    inv[0]  = ( m[5] * c5 - m[6] * c4 + m[7] * c3) * id;
    inv[1]  = (-m[1] * c5 + m[2] * c4 - m[3] * c3) * id;
    inv[2]  = ( m[13] * s5 - m[14] * s4 + m[15] * s3) * id;
    inv[3]  = (-m[9] * s5 + m[10] * s4 - m[11] * s3) * id;
    inv[4]  = (-m[4] * c5 + m[6] * c2 - m[7] * c1) * id;
    inv[5]  = ( m[0] * c5 - m[2] * c2 + m[3] * c1) * id;
    inv[6]  = (-m[12] * s5 + m[14] * s2 - m[15] * s1) * id;
    inv[7]  = ( m[8] * s5 - m[10] * s2 + m[11] * s1) * id;
    inv[8]  = ( m[4] * c4 - m[5] * c2 + m[7] * c0) * id;
    inv[9]  = (-m[0] * c4 + m[1] * c2 - m[3] * c0) * id;
    inv[10] = ( m[12] * s4 - m[13] * s2 + m[15] * s0) * id;
    inv[11] = (-m[8] * s4 + m[9] * s2 - m[11] * s0) * id;
    inv[12] = (-m[4] * c3 + m[5] * c1 - m[6] * c0) * id;
    inv[13] = ( m[0] * c3 - m[1] * c1 + m[2] * c0) * id;
    inv[14] = (-m[12] * s3 + m[13] * s1 - m[14] * s0) * id;
    inv[15] = ( m[8] * s3 - m[9] * s1 + m[10] * s0) * id;
}

// One thread per batch; 256 batches per 256-thread block. B % 256 == 0
// (B = 262144 in this problem), so no tail guards — shorter live ranges,
// no exec-mask churn. All large global traffic staged through one reused
// 36.9 KB LDS buffer with coalesced global access.
// NOTE: no min-waves clause in launch_bounds — round 2 showed forcing 3
// waves/EU makes the allocator spill ~100 regs to scratch (+135 MB writes).
__global__ __launch_bounds__(256) void ekf_kernel(
    const float* __restrict__ meas,   // (B,4)
    const float* __restrict__ state,  // (B,8)
    const float* __restrict__ Pin,    // (B,8,8) symmetric
    const float* __restrict__ Fin,    // (B,8,8)
    const float* __restrict__ Hin,    // (B,4,8)
    const float* __restrict__ pnin,   // (B,36)
    const float* __restrict__ mnin,   // (B,10)
    float* __restrict__ out_pred,     // (B,4)
    float* __restrict__ out_state,    // (B,8)
    float* __restrict__ out_cov)      // (B,8,8)
{
    const int t  = threadIdx.x;
    const int bb = blockIdx.x * 256;          // batch base of this block
    const int b  = bb + t;

    __shared__ float4 buf[2304];              // 256 * 9 float4 = 36,864 B

    // ============ stage pn (9 f4/batch, straight copy) -> Q into Pn ============
    {
        const float4* g = reinterpret_cast<const float4*>(pnin) + (size_t)bb * 9;
        #pragma unroll
        for (int i = 0; i < 9; ++i) buf[i * 256 + t] = g[i * 256 + t];
    }
    __syncthreads();
    float Pn[36];  // becomes new_state_cov; init with Q
    {
        float Lq[36];
        #pragma unroll
        for (int q = 0; q < 9; ++q) {
            float4 v = buf[t * 9 + q];
            Lq[4 * q] = v.x; Lq[4 * q + 1] = v.y; Lq[4 * q + 2] = v.z; Lq[4 * q + 3] = v.w;
        }
        #pragma unroll
        for (int i = 0; i < 8; ++i)
            #pragma unroll
            for (int j = 0; j <= i; ++j) {
                float acc = 0.f;
                #pragma unroll
                for (int k = 0; k <= j; ++k)
                    acc += Lq[TIX(i, k)] * Lq[TIX(j, k)];
                Pn[TIX(i, j)] = acc;
            }
    }
    __syncthreads();

    // ============ stage state (2 f4/batch, pad-3 layout) ============
    {
        const float4* g = reinterpret_cast<const float4*>(state) + (size_t)bb * 2;
        #pragma unroll
        for (int i = 0; i < 2; ++i) {
            int f = i * 256 + t;
            buf[(f >> 1) * 3 + (f & 1)] = g[f];
        }
    }
    __syncthreads();
    float s[8];
    {
        float4 a = buf[t * 3 + 0], c = buf[t * 3 + 1];
        s[0] = a.x; s[1] = a.y; s[2] = a.z; s[3] = a.w;
        s[4] = c.x; s[5] = c.y; s[6] = c.z; s[7] = c.w;
    }
    __syncthreads();

    // ============ stage P in two halves (8 f4/batch each, pad-9) -> Ps packed ============
    float Ps[36];
    #pragma unroll
    for (int h = 0; h < 2; ++h) {
        {
            const float4* g = reinterpret_cast<const float4*>(Pin) + (size_t)bb * 16;
            #pragma unroll
            for (int i = 0; i < 8; ++i) {
                int fl = i * 256 + t;
                int bq = fl >> 3, q = fl & 7;
                buf[bq * 9 + q] = g[bq * 16 + 8 * h + q];
            }
        }
        __syncthreads();
        #pragma unroll
        for (int q = 0; q < 8; ++q) {
            float4 v = buf[t * 9 + q];
            const int row = 4 * h + (q >> 1), c0 = 4 * (q & 1);
            if (c0 + 0 <= row) Ps[TIX(row, c0 + 0)] = v.x;
            if (c0 + 1 <= row) Ps[TIX(row, c0 + 1)] = v.y;
            if (c0 + 2 <= row) Ps[TIX(row, c0 + 2)] = v.z;
            if (c0 + 3 <= row) Ps[TIX(row, c0 + 3)] = v.w;
        }
        __syncthreads();
    }

    // ============ stage F in two halves -> Fm[64] ============
    float Fm[64];
    #pragma unroll
    for (int h = 0; h < 2; ++h) {
        {
            const float4* g = reinterpret_cast<const float4*>(Fin) + (size_t)bb * 16;
            #pragma unroll
            for (int i = 0; i < 8; ++i) {
                int fl = i * 256 + t;
                int bq = fl >> 3, q = fl & 7;
                buf[bq * 9 + q] = g[bq * 16 + 8 * h + q];
            }
        }
        __syncthreads();
        #pragma unroll
        for (int q = 0; q < 8; ++q) {
            float4 v = buf[t * 9 + q];
            Fm[32 * h + 4 * q + 0] = v.x;
            Fm[32 * h + 4 * q + 1] = v.y;
            Fm[32 * h + 4 * q + 2] = v.z;
            Fm[32 * h + 4 * q + 3] = v.w;
        }
        __syncthreads();
    }

    // ============ predict ============
    float ns[8];
    #pragma unroll
    for (int i = 0; i < 8; ++i) {
        float acc = 0.f;
        #pragma unroll
        for (int j = 0; j < 8; ++j) acc += Fm[i * 8 + j] * s[j];
        ns[i] = acc;
    }
    // newP = F P F^T + Q, column block at a time (no T[64])
    #pragma unroll
    for (int l = 0; l < 8; ++l) {
        float gcol[8];  // gcol[j] = (P F^T)[j][l] = sum_k P[j,k] F[l,k]
        #pragma unroll
        for (int j = 0; j < 8; ++j) {
            float acc = 0.f;
            #pragma unroll
            for (int k = 0; k < 8; ++k) acc += SYM(Ps, j, k) * Fm[l * 8 + k];
            gcol[j] = acc;
        }
        #pragma unroll
        for (int i = l; i < 8; ++i) {
            float acc = Pn[TIX(i, l)];
            #pragma unroll
            for (int j = 0; j < 8; ++j) acc += Fm[i * 8 + j] * gcol[j];
            Pn[TIX(i, l)] = acc;
        }
    }

    // ============ stage H (8 f4/batch straight global, pad-9 dest) -> Hm ============
    float Hm[32];
    {
        const float4* g = reinterpret_cast<const float4*>(Hin) + (size_t)bb * 8;
        #pragma unroll
        for (int i = 0; i < 8; ++i) {
            int fl = i * 256 + t;
            buf[(fl >> 3) * 9 + (fl & 7)] = g[fl];
        }
    }
    __syncthreads();
    #pragma unroll
    for (int q = 0; q < 8; ++q) {
        float4 v = buf[t * 9 + q];
        Hm[4 * q + 0] = v.x; Hm[4 * q + 1] = v.y;
        Hm[4 * q + 2] = v.z; Hm[4 * q + 3] = v.w;
    }
    __syncthreads();

    // ============ stage mn (5 f2/batch straight copy) -> Rs ============
    float Rs[10];
    {
        const float2* g = reinterpret_cast<const float2*>(mnin) + (size_t)bb * 5;
        float2* buf2 = reinterpret_cast<float2*>(buf);
        #pragma unroll
        for (int i = 0; i < 5; ++i) buf2[i * 256 + t] = g[i * 256 + t];
    }
    __syncthreads();
    {
        const float2* buf2 = reinterpret_cast<const float2*>(buf);
        float Lr[10];
        #pragma unroll
        for (int p = 0; p < 5; ++p) {
            float2 v = buf2[t * 5 + p];
            Lr[2 * p] = v.x; Lr[2 * p + 1] = v.y;
        }
        #pragma unroll
        for (int i = 0; i < 4; ++i)
            #pragma unroll
            for (int j = 0; j <= i; ++j) {
                float acc = 0.f;
                #pragma unroll
                for (int k = 0; k <= j; ++k)
                    acc += Lr[TIX(i, k)] * Lr[TIX(j, k)];
                Rs[TIX(i, j)] = acc;
            }
    }
    __syncthreads();

    // ============ update (all in registers) ============
    float pred[4], res[4], HP[32], Si[16], K[32], us[8];
    {
        float4 z = *(reinterpret_cast<const float4*>(meas) + b);
        const float zz[4] = {z.x, z.y, z.z, z.w};
        #pragma unroll
        for (int i = 0; i < 4; ++i) {
            float acc = 0.f;
            #pragma unroll
            for (int j = 0; j < 8; ++j) acc += Hm[i * 8 + j] * ns[j];
            pred[i] = acc;
            res[i] = zz[i] - acc;
        }

        // HP = H * newP (4x8); PHt = HP^T by symmetry of newP
        #pragma unroll
        for (int i = 0; i < 4; ++i)
            #pragma unroll
            for (int k = 0; k < 8; ++k) {
                float acc = 0.f;
                #pragma unroll
                for (int j = 0; j < 8; ++j) acc += Hm[i * 8 + j] * SYM(Pn, j, k);
                HP[i * 8 + k] = acc;
            }

        // S = HP H^T + R -> inverse
        float Sf[16];
        #pragma unroll
        for (int i = 0; i < 4; ++i)
            #pragma unroll
            for (int l = 0; l < 4; ++l) {
                float acc = SYM(Rs, i, l);
                #pragma unroll
                for (int k = 0; k < 8; ++k) acc += HP[i * 8 + k] * Hm[l * 8 + k];
                Sf[i * 4 + l] = acc;
            }
        inv4(Sf, Si);

        // K = PHt * Si (8x4)
        #pragma unroll
        for (int i = 0; i < 8; ++i)
            #pragma unroll
            for (int j = 0; j < 4; ++j) {
                float acc = 0.f;
                #pragma unroll
                for (int k = 0; k < 4; ++k) acc += HP[k * 8 + i] * Si[k * 4 + j];
                K[i * 4 + j] = acc;
            }

        // pred out (direct: 16B/lane contiguous, fully coalesced)
        *(reinterpret_cast<float4*>(out_pred) + b) =
            make_float4(pred[0], pred[1], pred[2], pred[3]);

        #pragma unroll
        for (int i = 0; i < 8; ++i) {
            float acc = ns[i];
            #pragma unroll
            for (int j = 0; j < 4; ++j) acc += K[i * 4 + j] * res[j];
            us[i] = acc;
        }
    }

    // ============ stage upd_state out (pad-3 layout) ============
    __syncthreads();
    buf[t * 3 + 0] = make_float4(us[0], us[1], us[2], us[3]);
    buf[t * 3 + 1] = make_float4(us[4], us[5], us[6], us[7]);
    __syncthreads();
    {
        float4* g = reinterpret_cast<float4*>(out_state) + (size_t)bb * 2;
        #pragma unroll
        for (int i = 0; i < 2; ++i) {
            int f = i * 256 + t;
            g[f] = buf[(f >> 1) * 3 + (f & 1)];
        }
    }
    __syncthreads();

    // ============ upd_cov = (I - K H) newP, two row-halves through LDS ============
    #pragma unroll
    for (int h = 0; h < 2; ++h) {
        #pragma unroll
        for (int r = 0; r < 4; ++r) {
            const int i = 4 * h + r;
            float Arow[8];
            #pragma unroll
            for (int j = 0; j < 8; ++j) {
                float acc = (i == j) ? 1.f : 0.f;
                #pragma unroll
                for (int k = 0; k < 4; ++k) acc -= K[i * 4 + k] * Hm[k * 8 + j];
                Arow[j] = acc;
            }
            float orow[8];
            #pragma unroll
            for (int j = 0; j < 8; ++j) {
                float acc = 0.f;
                #pragma unroll
                for (int k = 0; k < 8; ++k) acc += Arow[k] * SYM(Pn, k, j);
                orow[j] = acc;
            }
            buf[t * 9 + 2 * r + 0] = make_float4(orow[0], orow[1], orow[2], orow[3]);
            buf[t * 9 + 2 * r + 1] = make_float4(orow[4], orow[5], orow[6], orow[7]);
        }
        __syncthreads();
        {
            float4* g = reinterpret_cast<float4*>(out_cov) + (size_t)bb * 16;
            #pragma unroll
            for (int i = 0; i < 8; ++i) {
                int fl = i * 256 + t;
                int bq = fl >> 3, q = fl & 7;
                g[bq * 16 + 8 * h + q] = buf[bq * 9 + q];
            }
        }
        __syncthreads();
    }
}

extern "C" void kernel_launch(void* const* d_in, const int* in_sizes, int n_in,
                              void* d_out, int out_size, void* d_ws, size_t ws_size,
                              hipStream_t stream) {
    const float* meas  = (const float*)d_in[0];
    const float* state = (const float*)d_in[1];
    const float* Pin   = (const float*)d_in[2];
    const float* Fin   = (const float*)d_in[3];
    const float* Hin   = (const float*)d_in[4];
    const float* pn    = (const float*)d_in[5];
    const float* mn    = (const float*)d_in[6];

    const int B = in_sizes[1] / 8;  // state is (B, 8); B = 262144 (divisible by 256)

    float* out = (float*)d_out;
    float* out_pred  = out;                       // B*4
    float* out_state = out + (size_t)B * 4;       // B*8
    float* out_cov   = out + (size_t)B * 12;      // B*64

    dim3 block(256);
    dim3 grid(B / 256);
    ekf_kernel<<<grid, block, 0, stream>>>(meas, state, Pin, Fin, Hin, pn, mn,
                                           out_pred, out_state, out_cov);
}